// Round 18
// baseline (278.552 us; speedup 1.0000x reference)
//
#include <hip/hip_runtime.h>

#define DEV __device__ __forceinline__

typedef __attribute__((ext_vector_type(8))) short short8;
typedef __attribute__((ext_vector_type(4))) float f32x4;
typedef __attribute__((ext_vector_type(4))) unsigned short ushort4_t;
typedef __attribute__((ext_vector_type(4))) unsigned int uint4_t;

namespace {
constexpr int D_ = 256, C_ = 10, T_ = 15, H_ = 5, ENC_ = 64, L_ = 16;
constexpr int NS_ = 2048, NQ_ = 32768;
constexpr int P_ = 60240, SW_ = 57600, SB_ = 225, LF_ = 2400;
constexpr int FEAT_ = 128;
constexpr int G_ = 75;                      // H*T groups
constexpr int GSPLIT_ = 3;                  // interleaved chunks: g == gc (mod 3)
constexpr int WGB_ = 16384;                 // bytes per group W-image
constexpr int NBLK_ = 128;                  // encoder blocks per head

// workspace layout (in floats)
constexpr size_t OFF_CP   = 0;                                  // 5*128*64 partial ctx sums
constexpr size_t OFF_PVEC = OFF_CP + (size_t)H_*NBLK_*ENC_;
constexpr size_t OFF_TMP  = OFF_PVEC + (size_t)H_*FEAT_;
constexpr size_t OFF_SB   = OFF_TMP + 8;                        // 75*16 padded sb (stride 16)
constexpr size_t OFF_LRAW = OFF_SB + (size_t)G_*16 + 16;
constexpr size_t OFF_TRAW = OFF_LRAW + (size_t)H_*T_*L_*C_;
constexpr size_t OFF_SL   = OFF_TRAW + (size_t)H_*T_;
constexpr size_t OFF_WBF  = OFF_SL + (size_t)H_*T_*L_*C_;       // 75*16384B
constexpr size_t OFF_SLA  = OFF_WBF + (size_t)G_*WGB_/4;        // 75*1024B
constexpr size_t OFF_OUTP = OFF_SLA + (size_t)G_*1024/4;        // 3*NQ*10 partials
constexpr size_t WS_NEED_FLOATS = OFF_OUTP + (size_t)GSPLIT_*NQ_*10;
} // namespace

DEV float wave_sum(float v) {
  #pragma unroll
  for (int o = 32; o; o >>= 1) v += __shfl_xor(v, o, 64);
  return v;
}
DEV float gelu_exact(float x) { return 0.5f * x * (1.f + erff(x * 0.70710678118654752f)); }
DEV unsigned short f2bf(float x) {            // RNE bf16
  unsigned u = __float_as_uint(x);
  return (unsigned short)((u + 0x7FFFu + ((u >> 16) & 1u)) >> 16);
}
DEV float bf2f(unsigned short b) { return __uint_as_float(((unsigned)b) << 16); }
DEV unsigned cvt_pk_bf16(float lo, float hi) {
  unsigned d;
  asm("v_cvt_pk_bf16_f32 %0, %1, %2" : "=v"(d) : "v"(lo), "v"(hi));
  return d;
}
DEV float fast_rcp(float x) {                 // raw v_rcp_f32 (~1 ulp)
  float r;
  asm("v_rcp_f32 %0, %1" : "=v"(r) : "v"(x));
  return r;
}
// async global -> LDS DMA, 16B per lane; lds dest = uniform base + lane*16 (HW adds lane offset)
DEV void gload16(const char* g, char* l) {
  __builtin_amdgcn_global_load_lds(
      (const __attribute__((address_space(1))) void*)g,
      (__attribute__((address_space(3))) void*)l, 16, 0, 0);
}

// ---------------- fused encoder: enc2(enc1(X)) reduced in-block to ctx partials ----------------
__global__ __launch_bounds__(256) void enc12_kernel(
    const float* __restrict__ Xbase,
    const float* __restrict__ W1, const float* __restrict__ B1,
    const float* __restrict__ G1, const float* __restrict__ Be1,
    const float* __restrict__ W2, const float* __restrict__ B2,
    const float* __restrict__ G2, const float* __restrict__ Be2,
    float* __restrict__ Partial)
{
  __shared__ float xs[4][4][ENC_];     // [wave][row][col] = 4 KB
  __shared__ float red[4][ENC_];
  const int h = blockIdx.y;
  const int lane = threadIdx.x & 63;
  const int wv = threadIdx.x >> 6;
  const int row0 = blockIdx.x * 16 + wv * 4;

  { // ---- enc1: K=256 from global ----
    constexpr int K = 256;
    const float* __restrict__ X = Xbase + (size_t)row0 * K;
    const float* __restrict__ wc = W1 + (size_t)h * K * ENC_ + lane;
    float a0 = 0.f, a1 = 0.f, a2 = 0.f, a3 = 0.f;
    #pragma unroll 4
    for (int k = 0; k < K; ++k) {
      const float wkl = wc[(size_t)k * ENC_];
      a0 = fmaf(X[k],       wkl, a0);
      a1 = fmaf(X[K + k],   wkl, a1);
      a2 = fmaf(X[2*K + k], wkl, a2);
      a3 = fmaf(X[3*K + k], wkl, a3);
    }
    const float bb = B1[h*ENC_ + lane];
    const float gg = G1[h*ENC_ + lane], be = Be1[h*ENC_ + lane];
    float acc[4] = {a0 + bb, a1 + bb, a2 + bb, a3 + bb};
    #pragma unroll
    for (int r = 0; r < 4; ++r) {
      const float m = wave_sum(acc[r]) * (1.f / ENC_);
      const float d = acc[r] - m;
      const float var = wave_sum(d * d) * (1.f / ENC_);
      const float y = d * rsqrtf(var + 1e-5f) * gg + be;
      xs[wv][r][lane] = gelu_exact(y);
    }
  }
  __syncthreads();
  { // ---- enc2: K=64 from LDS (wave-local rows), then in-block ctx partial reduce ----
    constexpr int K = 64;
    const float* __restrict__ wc = W2 + (size_t)h * K * ENC_ + lane;
    float a0 = 0.f, a1 = 0.f, a2 = 0.f, a3 = 0.f;
    #pragma unroll 4
    for (int k = 0; k < K; ++k) {
      const float wkl = wc[(size_t)k * ENC_];
      a0 = fmaf(xs[wv][0][k], wkl, a0);
      a1 = fmaf(xs[wv][1][k], wkl, a1);
      a2 = fmaf(xs[wv][2][k], wkl, a2);
      a3 = fmaf(xs[wv][3][k], wkl, a3);
    }
    const float bb = B2[h*ENC_ + lane];
    const float gg = G2[h*ENC_ + lane], be = Be2[h*ENC_ + lane];
    float acc[4] = {a0 + bb, a1 + bb, a2 + bb, a3 + bb};
    float psum = 0.f;
    #pragma unroll
    for (int r = 0; r < 4; ++r) {
      const float m = wave_sum(acc[r]) * (1.f / ENC_);
      const float d = acc[r] - m;
      const float var = wave_sum(d * d) * (1.f / ENC_);
      const float y = d * rsqrtf(var + 1e-5f) * gg + be;
      psum += gelu_exact(y);
    }
    red[wv][lane] = psum;
    __syncthreads();
    if (wv == 0) {
      const float tot = red[0][lane] + red[1][lane] + red[2][lane] + red[3][lane];
      Partial[((size_t)h * NBLK_ + blockIdx.x) * ENC_ + lane] = tot;
    }
  }
}

// ---------------- reduce ctx partials + temperature + pvec, 128 threads/head ----------------
__global__ __launch_bounds__(128) void pvec_kernel(
    const float* __restrict__ Partial, const float* __restrict__ temperature,
    const float* __restrict__ w1, const float* __restrict__ b1,
    const float* __restrict__ g, const float* __restrict__ b,
    float* __restrict__ pvec, float* __restrict__ tmp)
{
  __shared__ float red[128];
  __shared__ float ctxl[ENC_];
  __shared__ float sred[2];
  const int h = blockIdx.x, tid = threadIdx.x;
  const int e = tid & 63, half = tid >> 6;
  float s = 0.f;
  const float* __restrict__ pp = Partial + (size_t)h * NBLK_ * ENC_ + e;
  #pragma unroll 4
  for (int bb = half * 64; bb < half * 64 + 64; ++bb) s += pp[(size_t)bb * ENC_];
  red[tid] = s;
  __syncthreads();
  if (half == 0) ctxl[e] = (red[e] + red[64 + e]) * (1.f / NS_);
  if (h == 0 && tid == 0) {
    const float t = fminf(fmaxf(temperature[0], 0.1f), 2.0f);
    tmp[0] = t; tmp[1] = 1.f / t;
  }
  __syncthreads();
  const int j = tid;
  float acc = b1[h * FEAT_ + j];
  #pragma unroll 4
  for (int e2 = 0; e2 < ENC_; ++e2)
    acc = fmaf(ctxl[e2], w1[((size_t)h * ENC_ + e2) * FEAT_ + j], acc);
  const int lane = j & 63, wvv = j >> 6;
  const float ps = wave_sum(acc);
  if (lane == 0) sred[wvv] = ps;
  __syncthreads();
  const float m = (sred[0] + sred[1]) * (1.f / FEAT_);
  const float d = acc - m;
  const float vs = wave_sum(d * d);
  __syncthreads();
  if (lane == 0) sred[wvv] = vs;
  __syncthreads();
  const float var = (sred[0] + sred[1]) * (1.f / FEAT_);
  const float y = d * rsqrtf(var + 1e-5f) * g[h * FEAT_ + j] + b[h * FEAT_ + j];
  pvec[h * FEAT_ + j] = gelu_exact(y);
}

// ---------------- params = tanh(p @ pg_w2 + pg_b2)*2 → W bf16 hi/lo image + sb/leaf/tree ----------------
__global__ __launch_bounds__(256) void params_kernel(
    const float* __restrict__ pvec, const float* __restrict__ w2,
    const float* __restrict__ b2, const float* __restrict__ tmp,
    char* __restrict__ WbfB, float* __restrict__ sbv,
    float* __restrict__ lraw, float* __restrict__ traw)
{
  __shared__ float pl[FEAT_];
  const int h = blockIdx.y;
  if (threadIdx.x < FEAT_) pl[threadIdx.x] = pvec[h * FEAT_ + threadIdx.x];
  __syncthreads();
  const int j4 = blockIdx.x * 1024 + threadIdx.x * 4;
  if (j4 >= P_) return;
  const float it = tmp[1];
  float4 acc = *reinterpret_cast<const float4*>(b2 + (size_t)h * P_ + j4);
  const float* __restrict__ wp = w2 + (size_t)h * FEAT_ * P_ + j4;
  #pragma unroll 4
  for (int k = 0; k < FEAT_; ++k) {
    const float pk = pl[k];
    const float4 wv = *reinterpret_cast<const float4*>(wp + (size_t)k * P_);
    acc.x = fmaf(pk, wv.x, acc.x);
    acc.y = fmaf(pk, wv.y, acc.y);
    acc.z = fmaf(pk, wv.z, acc.z);
    acc.w = fmaf(pk, wv.w, acc.w);
  }
  const float vals[4] = {acc.x, acc.y, acc.z, acc.w};
  if (j4 < SW_) {
    const int t = j4 / 3840, rem = j4 - t * 3840, i = rem >> 8, d = rem & 255;
    const int g = h * T_ + t;
    ushort4_t hs, ls;
    #pragma unroll
    for (int q = 0; q < 4; ++q) {
      const float v = tanhf(vals[q]) * 2.f * it;
      const unsigned short hb = f2bf(v);
      hs[q] = hb;
      ls[q] = f2bf(v - bf2f(hb));
    }
    const unsigned off = (unsigned)(i * 512 + d * 2) ^ ((unsigned)(i & 15) << 4);
    char* base = WbfB + (size_t)g * WGB_;
    *(ushort4_t*)(base + off) = hs;
    *(ushort4_t*)(base + 8192 + off) = ls;
  } else {
    #pragma unroll
    for (int q = 0; q < 4; ++q) {
      const int j = j4 + q;
      const float v = tanhf(vals[q]) * 2.f;
      if (j < SW_ + SB_) {
        const int jj = j - SW_;                 // 0..224 within head: t = jj/15, i = jj%15
        sbv[((size_t)h * T_ + jj / 15) * 16 + (jj % 15)] = v * it;   // padded stride 16
      }
      else if (j < SW_ + SB_ + LF_) lraw[h * LF_ + (j - SW_ - SB_)] = v;
      else                          traw[h * T_ + (j - SW_ - SB_ - LF_)] = v;
    }
  }
}

// ---------------- finalize, parallelized: one block per group ----------------
__global__ __launch_bounds__(256) void finalize_kernel(
    const float* __restrict__ head_weights, const float* __restrict__ traw,
    const float* __restrict__ lraw, const float* __restrict__ tmp,
    float* __restrict__ sl, char* __restrict__ slA, char* __restrict__ WbfB,
    float* __restrict__ sbv)
{
  const int g = blockIdx.x;          // 0..74
  const int h = g / T_;
  const int tid = threadIdx.x;
  __shared__ float wtg;
  if (tid < 128) {                   // zero pad row i=15 of this group's W image (hi+lo)
    char* base = WbfB + (size_t)g * WGB_ + 15 * 512 + tid * 4;
    *(unsigned*)base = 0u;
    *(unsigned*)(base + 8192) = 0u;
  } else if (tid == 128) {
    sbv[g * 16 + 15] = 0.f;          // sb pad slot
  } else if (tid == 129) {
    float m = -1e30f;
    for (int hh = 0; hh < H_; ++hh) m = fmaxf(m, head_weights[hh]);
    float s = 0.f;
    for (int hh = 0; hh < H_; ++hh) s += __expf(head_weights[hh] - m);
    const float hwv = __expf(head_weights[h] - m) / s;
    float mt = -1e30f;
    for (int t = 0; t < T_; ++t) mt = fmaxf(mt, traw[h * T_ + t]);
    float st = 0.f;
    for (int t = 0; t < T_; ++t) st += __expf(traw[h * T_ + t] - mt);
    wtg = hwv * __expf(traw[g] - mt) / st;
  }
  __syncthreads();
  const float it = tmp[1];
  if (tid < L_) {                    // scaled leaf softmax, one row per thread
    const int row = g * L_ + tid;
    const float* __restrict__ lr = lraw + (size_t)row * C_;
    float m = -1e30f;
    #pragma unroll
    for (int c = 0; c < C_; ++c) m = fmaxf(m, lr[c]);
    float e[C_]; float s = 0.f;
    #pragma unroll
    for (int c = 0; c < C_; ++c) { e[c] = __expf((lr[c] - m) * it); s += e[c]; }
    const float sc = wtg / s;
    #pragma unroll
    for (int c = 0; c < C_; ++c) sl[(size_t)row * C_ + c] = e[c] * sc;
  }
  __syncthreads();
  if (tid < 64) {                    // slA A-fragment image pack
    const int p = tid, c = p & 15, kg = p >> 4;
    ushort4_t w0, w1;
    #pragma unroll
    for (int j = 0; j < 8; ++j) {
      const int l = kg * 8 + j;
      const unsigned short v = (l < 16 && c < 10) ? f2bf(sl[(size_t)(g * 16 + l) * C_ + c]) : (unsigned short)0;
      if (j < 4) w0[j] = v; else w1[j - 4] = v;
    }
    *(ushort4_t*)(slA + (size_t)(g * 64 + p) * 16) = w0;
    *(ushort4_t*)(slA + (size_t)(g * 64 + p) * 16 + 8) = w1;
  }
}

// ---------------- fused MFMA query kernel: 128 q/block (4 waves x 32q = 2 tiles) ----------------
// INTERLEAVED GSPLIT x3: chunk gc processes g = gc, gc+3, gc+6, ... so all blocks on an XCD
// touch the same ~48KB W window simultaneously (reuse distance ~0 -> survives Xq L2 eviction).
// 3 blocks/CU (LDS 120KB, VGPR<=170). B-frag ds_reads shared across 2 A-tiles.
__global__ __launch_bounds__(256, 3) void qk_kernel(
    const float* __restrict__ Xq, const char* __restrict__ WbfB,
    const char* __restrict__ slA, const float* __restrict__ sbvP,
    float* __restrict__ outP)
{
  __shared__ char lds[40960];       // [0,32768): W dbuf (2x16KB); [32768,40960): 4x2KB tw
  const int tid  = threadIdx.x;
  const int lane = tid & 63;
  const int wv   = tid >> 6;
  const int n0   = blockIdx.x * 128;
  const int gc   = blockIdx.y;      // 0..2, g == gc (mod 3)
  const int lrow = lane & 15;       // A row (query within tile) / B col (i) / leaf-A row (c)
  const int lkg  = lane >> 4;       // k-group 0..3 == leaf-quad owned

  // ---- A-fragments: 2 tiles of 16 queries (hi/lo bf16) ----
  short8 Ah[2][8], Al[2][8];
  #pragma unroll
  for (int rt = 0; rt < 2; ++rt) {
    const float* xr = Xq + (size_t)(n0 + wv * 32 + rt * 16 + lrow) * 256 + lkg * 8;
    #pragma unroll
    for (int ks = 0; ks < 8; ++ks) {
      const f32x4 a = *(const f32x4*)(xr + ks * 32);
      const f32x4 b = *(const f32x4*)(xr + ks * 32 + 4);
      short8 hh, ll;
      #pragma unroll
      for (int j = 0; j < 4; ++j) {
        unsigned short hb = f2bf(a[j]);
        hh[j] = (short)hb; ll[j] = (short)f2bf(a[j] - bf2f(hb));
        hb = f2bf(b[j]);
        hh[4 + j] = (short)hb; ll[4 + j] = (short)f2bf(b[j] - bf2f(hb));
      }
      Ah[rt][ks] = hh; Al[rt][ks] = ll;
    }
  }

  // DMA one group's 16KB W image into buf (each wave stages its 4KB segment)
  auto DMA = [&](int g, int buf) {
    const char* src = WbfB + (size_t)g * WGB_;
    char* dst = lds + buf * WGB_;
    #pragma unroll
    for (int it = 0; it < 4; ++it) {
      const int seg = wv * 4096 + it * 1024;
      gload16(src + seg + lane * 16, dst + seg);
    }
  };

  // ---- prologue: DMA first group into buf0 ----
  DMA(gc, 0);
  __syncthreads();                  // drains vmcnt -> buf0 ready

  char* tw = lds + 32768 + wv * 2048;   // per-wave 2-tile logit transpose (zero-conflict layout)
  const int q  = lane & 15;             // query owned in the epilogue (per tile)
  const int h2 = lkg >> 1;

  // ---- g-invariant epilogue constants (hoisted) ----
  const int sI1 = 1 + h2, sI2 = 3 + lkg, sI3 = 7 + 2 * lkg, sI4 = 8 + 2 * lkg;
  auto twAddr = [&](int c, int qt) -> unsigned {
    return (unsigned)(c * 128 + qt * 4) ^ ((unsigned)(c & 7) << 4);
  };
  const unsigned tA0_0 = twAddr(0, q),        tA0_1 = twAddr(0, 16 + q);
  const unsigned tA1_0 = twAddr(sI1, q),      tA1_1 = twAddr(sI1, 16 + q);
  const unsigned tA2_0 = twAddr(sI2, q),      tA2_1 = twAddr(sI2, 16 + q);
  const unsigned tA3_0 = twAddr(sI3, q),      tA3_1 = twAddr(sI3, 16 + q);
  const unsigned tA4_0 = twAddr(sI4, q),      tA4_1 = twAddr(sI4, 16 + q);
  const int idx0 = ((lkg & 1) << 5) + q;   // src lane for quad 2*kg
  const int idx1 = idx0 + 16;              // src lane for quad 2*kg+1
  const bool act = (lkg < 2);              // B rows k>=16 are zero
  const unsigned wA0 = (unsigned)(lrow * 128 + (0 * 16 + lkg * 4) * 4) ^ ((unsigned)(lrow & 7) << 4);
  const unsigned wA1 = (unsigned)(lrow * 128 + (1 * 16 + lkg * 4) * 4) ^ ((unsigned)(lrow & 7) << 4);

  f32x4 Cac0 = {0.f, 0.f, 0.f, 0.f}, Cac1 = {0.f, 0.f, 0.f, 0.f};

  int cur = 0;
  for (int g = gc; g < G_; g += 3) {
    // per-group operands FIRST (oldest in VMEM FIFO -> their waits never drain the DMA)
    const short8 Asl = *(const short8*)(slA + (size_t)g * 1024 + lane * 16);
    const float* sbg = sbvP + (size_t)g * 16;
    const float s0v = sbg[0], s1v = sbg[sI1], s2v = sbg[sI2], s3v = sbg[sI3], s4v = sbg[sI4];
    if (g + 3 < G_) DMA(g + 3, cur ^ 1);

    const char* bb = lds + cur * WGB_;
    // 16 shared B-frag reads feed 6 independent 8-deep chains (3 per tile)
    f32x4 Ch0 = {0,0,0,0}, Cm10 = {0,0,0,0}, Cm20 = {0,0,0,0};
    f32x4 Ch1 = {0,0,0,0}, Cm11 = {0,0,0,0}, Cm21 = {0,0,0,0};
    __builtin_amdgcn_s_setprio(1);
    #pragma unroll
    for (int ks = 0; ks < 8; ++ks) {
      const unsigned adr = (unsigned)(lrow * 512 + ks * 64 + lkg * 16) ^ ((unsigned)lrow << 4);
      const short8 bh = *(const short8*)(bb + adr);
      const short8 bl = *(const short8*)(bb + 8192 + adr);
      Ch0  = __builtin_amdgcn_mfma_f32_16x16x32_bf16(Ah[0][ks], bh, Ch0,  0, 0, 0);
      Cm10 = __builtin_amdgcn_mfma_f32_16x16x32_bf16(Ah[0][ks], bl, Cm10, 0, 0, 0);
      Cm20 = __builtin_amdgcn_mfma_f32_16x16x32_bf16(Al[0][ks], bh, Cm20, 0, 0, 0);
      Ch1  = __builtin_amdgcn_mfma_f32_16x16x32_bf16(Ah[1][ks], bh, Ch1,  0, 0, 0);
      Cm11 = __builtin_amdgcn_mfma_f32_16x16x32_bf16(Ah[1][ks], bl, Cm11, 0, 0, 0);
      Cm21 = __builtin_amdgcn_mfma_f32_16x16x32_bf16(Al[1][ks], bh, Cm21, 0, 0, 0);
    }
    __builtin_amdgcn_s_setprio(0);
    // transpose logits through per-wave LDS (both tiles)
    {
      f32x4 cs0, cs1;
      #pragma unroll
      for (int r = 0; r < 4; ++r) { cs0[r] = Ch0[r] + Cm10[r] + Cm20[r]; cs1[r] = Ch1[r] + Cm11[r] + Cm21[r]; }
      *(f32x4*)(tw + wA0) = cs0;
      *(f32x4*)(tw + wA1) = cs1;
    }
    // quad-cone epilogue per tile: 5 sigmoids + tree -> leaves 4*lkg..4*lkg+3 of query q
    auto leaf = [&](unsigned a0, unsigned a1, unsigned a2, unsigned a3, unsigned a4, f32x4& CacT) {
      const float lg0 = *(const float*)(tw + a0) + s0v;
      const float lg1 = *(const float*)(tw + a1) + s1v;
      const float lg2 = *(const float*)(tw + a2) + s2v;
      const float lg3 = *(const float*)(tw + a3) + s3v;
      const float lg4 = *(const float*)(tw + a4) + s4v;
      const float d0 = fast_rcp(1.f + __expf(-lg0));
      const float d1 = fast_rcp(1.f + __expf(-lg1));
      const float d2 = fast_rcp(1.f + __expf(-lg2));
      const float d3 = fast_rcp(1.f + __expf(-lg3));
      const float d4 = fast_rcp(1.f + __expf(-lg4));
      const float aq = (lkg >= 2) ? d0 : (1.f - d0);
      const float bq = aq * ((lkg & 1) ? d1 : (1.f - d1));
      const float c0 = bq * (1.f - d2), c1 = bq * d2;
      const float r0 = c0 * (1.f - d3), r1 = c0 * d3;
      const float r2 = c1 * (1.f - d4), r3 = c1 * d4;
      const unsigned Pa = cvt_pk_bf16(r0, r1);
      const unsigned Pb = cvt_pk_bf16(r2, r3);
      const unsigned g0w = __shfl(Pa, idx0, 64);
      const unsigned g1w = __shfl(Pb, idx0, 64);
      const unsigned g2w = __shfl(Pa, idx1, 64);
      const unsigned g3w = __shfl(Pb, idx1, 64);
      uint4_t bu;
      bu[0] = act ? g0w : 0u;
      bu[1] = act ? g1w : 0u;
      bu[2] = act ? g2w : 0u;
      bu[3] = act ? g3w : 0u;
      const short8 B0 = __builtin_bit_cast(short8, bu);
      CacT = __builtin_amdgcn_mfma_f32_16x16x32_bf16(Asl, B0, CacT, 0, 0, 0);
    };
    leaf(tA0_0, tA1_0, tA2_0, tA3_0, tA4_0, Cac0);
    leaf(tA0_1, tA1_1, tA2_1, tA3_1, tA4_1, Cac1);
    __syncthreads();                // drains DMA (g+3 ready) + all reads of buf[cur] done
    cur ^= 1;
  }

  // store partials: tile t, D[c][q] col=lane&15=q, row c=lkg*4+j
  float* base = outP + (size_t)gc * ((size_t)NQ_ * 10);
  #pragma unroll
  for (int j = 0; j < 4; ++j) {
    const int c = lkg * 4 + j;
    if (c < 10) {
      base[(size_t)(n0 + wv * 32 + q) * 10 + c]      = Cac0[j];
      base[(size_t)(n0 + wv * 32 + 16 + q) * 10 + c] = Cac1[j];
    }
  }
}

// ---------------- sum the 3 gchunk partials ----------------
__global__ __launch_bounds__(256) void reduce_kernel(const float* __restrict__ p, float* __restrict__ out)
{
  const size_t i = ((size_t)blockIdx.x * 256 + threadIdx.x) * 4;
  const f32x4 a = *(const f32x4*)(p + i);
  const f32x4 b = *(const f32x4*)(p + (size_t)NQ_ * 10 + i);
  const f32x4 c = *(const f32x4*)(p + (size_t)2 * NQ_ * 10 + i);
  f32x4 s;
  #pragma unroll
  for (int j = 0; j < 4; ++j) s[j] = a[j] + b[j] + c[j];
  *(f32x4*)(out + i) = s;
}

// ---------------- diagnostic marker: only runs if a launch failed ----------------
__global__ void mark_kernel(float* out, float v) { out[threadIdx.x] = v; }

extern "C" void kernel_launch(void* const* d_in, const int* in_sizes, int n_in,
                              void* d_out, int out_size, void* d_ws, size_t ws_size,
                              hipStream_t stream) {
  (void)in_sizes; (void)n_in; (void)out_size;
  const float* Xs          = (const float*)d_in[0];
  const float* Xq          = (const float*)d_in[1];
  const float* enc_w1      = (const float*)d_in[2];
  const float* enc_b1      = (const float*)d_in[3];
  const float* ln1_g       = (const float*)d_in[4];
  const float* ln1_b       = (const float*)d_in[5];
  const float* enc_w2      = (const float*)d_in[6];
  const float* enc_b2      = (const float*)d_in[7];
  const float* ln2_g       = (const float*)d_in[8];
  const float* ln2_b       = (const float*)d_in[9];
  const float* pg_w1       = (const float*)d_in[10];
  const float* pg_b1       = (const float*)d_in[11];
  const float* pg_ln_g     = (const float*)d_in[12];
  const float* pg_ln_b     = (const float*)d_in[13];
  const float* pg_w2       = (const float*)d_in[14];
  const float* pg_b2       = (const float*)d_in[15];
  const float* head_wts    = (const float*)d_in[16];
  const float* temperature = (const float*)d_in[17];

  float* ws   = (float*)d_ws;
  float* cpart= ws + OFF_CP;
  float* pvec = ws + OFF_PVEC;
  float* tmp  = ws + OFF_TMP;
  float* sbp  = ws + OFF_SB;
  float* lrw  = ws + OFF_LRAW;
  float* trw  = ws + OFF_TRAW;
  float* slp  = ws + OFF_SL;
  char*  wbf  = (char*)(ws + OFF_WBF);
  char*  slA  = (char*)(ws + OFF_SLA);
  float* outP = ws + OFF_OUTP;
  float* outp = (float*)d_out;

  unsigned mask = 0;
  (void)hipGetLastError();
  if (ws_size < WS_NEED_FLOATS * sizeof(float)) mask |= 0x80u;

  if (!mask) {
    enc12_kernel<<<dim3(NBLK_, 5), 256, 0, stream>>>(Xs, enc_w1, enc_b1, ln1_g, ln1_b,
                                                     enc_w2, enc_b2, ln2_g, ln2_b, cpart);
    if (hipGetLastError() != hipSuccess) mask |= 1u;
    pvec_kernel<<<5, 128, 0, stream>>>(cpart, temperature, pg_w1, pg_b1, pg_ln_g, pg_ln_b, pvec, tmp);
    if (hipGetLastError() != hipSuccess) mask |= 2u;
    params_kernel<<<dim3(59, 5), 256, 0, stream>>>(pvec, pg_w2, pg_b2, tmp, wbf, sbp, lrw, trw);
    if (hipGetLastError() != hipSuccess) mask |= 4u;
    finalize_kernel<<<G_, 256, 0, stream>>>(head_wts, trw, lrw, tmp, slp, slA, wbf, sbp);
    if (hipGetLastError() != hipSuccess) mask |= 8u;
    qk_kernel<<<dim3(NQ_ / 128, GSPLIT_), 256, 0, stream>>>(Xq, wbf, slA, sbp, outP);
    if (hipGetLastError() != hipSuccess) mask |= 16u;
    reduce_kernel<<<(NQ_ * 10) / (256 * 4), 256, 0, stream>>>(outP, outp);
    if (hipGetLastError() != hipSuccess) mask |= 32u;
  }
  if (mask) {
    mark_kernel<<<1, 16, 0, stream>>>(outp, 1024.f + 4.f * (float)mask);
    (void)hipGetLastError();
  }
}

// Round 19
// 156.771 us; speedup vs baseline: 1.7768x; 1.7768x over previous
//
#include <hip/hip_runtime.h>

#define DEV __device__ __forceinline__

typedef __attribute__((ext_vector_type(8))) short short8;
typedef __attribute__((ext_vector_type(4))) float f32x4;
typedef __attribute__((ext_vector_type(4))) unsigned short ushort4_t;
typedef __attribute__((ext_vector_type(4))) unsigned int uint4_t;

namespace {
constexpr int D_ = 256, C_ = 10, T_ = 15, H_ = 5, ENC_ = 64, L_ = 16;
constexpr int NS_ = 2048, NQ_ = 32768;
constexpr int P_ = 60240, SW_ = 57600, SB_ = 225, LF_ = 2400;
constexpr int FEAT_ = 128;
constexpr int G_ = 75;                      // H*T groups
constexpr int GSPLIT_ = 2;                  // group chunks (38 + 37)
constexpr int WGB_ = 16384;                 // bytes per group W-image
constexpr int NBLK_ = 128;                  // encoder blocks per head

// workspace layout (in floats)
constexpr size_t OFF_CP   = 0;                                  // 5*128*64 partial ctx sums
constexpr size_t OFF_PVEC = OFF_CP + (size_t)H_*NBLK_*ENC_;
constexpr size_t OFF_TMP  = OFF_PVEC + (size_t)H_*FEAT_;
constexpr size_t OFF_SB   = OFF_TMP + 8;                        // 75*16 padded sb (stride 16)
constexpr size_t OFF_LRAW = OFF_SB + (size_t)G_*16 + 16;
constexpr size_t OFF_TRAW = OFF_LRAW + (size_t)H_*T_*L_*C_;
constexpr size_t OFF_SL   = OFF_TRAW + (size_t)H_*T_;
constexpr size_t OFF_WBF  = OFF_SL + (size_t)H_*T_*L_*C_;       // 75*16384B
constexpr size_t OFF_SLA  = OFF_WBF + (size_t)G_*WGB_/4;        // 75*1024B
constexpr size_t OFF_OUTP = OFF_SLA + (size_t)G_*1024/4;        // 2*NQ*10 partials
constexpr size_t WS_NEED_FLOATS = OFF_OUTP + (size_t)GSPLIT_*NQ_*10;
} // namespace

DEV float wave_sum(float v) {
  #pragma unroll
  for (int o = 32; o; o >>= 1) v += __shfl_xor(v, o, 64);
  return v;
}
DEV float gelu_exact(float x) { return 0.5f * x * (1.f + erff(x * 0.70710678118654752f)); }
DEV unsigned short f2bf(float x) {            // RNE bf16
  unsigned u = __float_as_uint(x);
  return (unsigned short)((u + 0x7FFFu + ((u >> 16) & 1u)) >> 16);
}
DEV float bf2f(unsigned short b) { return __uint_as_float(((unsigned)b) << 16); }
DEV unsigned cvt_pk_bf16(float lo, float hi) {
  unsigned d;
  asm("v_cvt_pk_bf16_f32 %0, %1, %2" : "=v"(d) : "v"(lo), "v"(hi));
  return d;
}
DEV float fast_rcp(float x) {                 // raw v_rcp_f32 (~1 ulp)
  float r;
  asm("v_rcp_f32 %0, %1" : "=v"(r) : "v"(x));
  return r;
}
// async global -> LDS DMA, 16B per lane; lds dest = uniform base + lane*16 (HW adds lane offset)
DEV void gload16(const char* g, char* l) {
  __builtin_amdgcn_global_load_lds(
      (const __attribute__((address_space(1))) void*)g,
      (__attribute__((address_space(3))) void*)l, 16, 0, 0);
}

// ---------------- fused encoder: enc2(enc1(X)) reduced in-block to ctx partials ----------------
__global__ __launch_bounds__(256) void enc12_kernel(
    const float* __restrict__ Xbase,
    const float* __restrict__ W1, const float* __restrict__ B1,
    const float* __restrict__ G1, const float* __restrict__ Be1,
    const float* __restrict__ W2, const float* __restrict__ B2,
    const float* __restrict__ G2, const float* __restrict__ Be2,
    float* __restrict__ Partial)
{
  __shared__ float xs[4][4][ENC_];     // [wave][row][col] = 4 KB
  __shared__ float red[4][ENC_];
  const int h = blockIdx.y;
  const int lane = threadIdx.x & 63;
  const int wv = threadIdx.x >> 6;
  const int row0 = blockIdx.x * 16 + wv * 4;

  { // ---- enc1: K=256 from global ----
    constexpr int K = 256;
    const float* __restrict__ X = Xbase + (size_t)row0 * K;
    const float* __restrict__ wc = W1 + (size_t)h * K * ENC_ + lane;
    float a0 = 0.f, a1 = 0.f, a2 = 0.f, a3 = 0.f;
    #pragma unroll 4
    for (int k = 0; k < K; ++k) {
      const float wkl = wc[(size_t)k * ENC_];
      a0 = fmaf(X[k],       wkl, a0);
      a1 = fmaf(X[K + k],   wkl, a1);
      a2 = fmaf(X[2*K + k], wkl, a2);
      a3 = fmaf(X[3*K + k], wkl, a3);
    }
    const float bb = B1[h*ENC_ + lane];
    const float gg = G1[h*ENC_ + lane], be = Be1[h*ENC_ + lane];
    float acc[4] = {a0 + bb, a1 + bb, a2 + bb, a3 + bb};
    #pragma unroll
    for (int r = 0; r < 4; ++r) {
      const float m = wave_sum(acc[r]) * (1.f / ENC_);
      const float d = acc[r] - m;
      const float var = wave_sum(d * d) * (1.f / ENC_);
      const float y = d * rsqrtf(var + 1e-5f) * gg + be;
      xs[wv][r][lane] = gelu_exact(y);
    }
  }
  __syncthreads();
  { // ---- enc2: K=64 from LDS (wave-local rows), then in-block ctx partial reduce ----
    constexpr int K = 64;
    const float* __restrict__ wc = W2 + (size_t)h * K * ENC_ + lane;
    float a0 = 0.f, a1 = 0.f, a2 = 0.f, a3 = 0.f;
    #pragma unroll 4
    for (int k = 0; k < K; ++k) {
      const float wkl = wc[(size_t)k * ENC_];
      a0 = fmaf(xs[wv][0][k], wkl, a0);
      a1 = fmaf(xs[wv][1][k], wkl, a1);
      a2 = fmaf(xs[wv][2][k], wkl, a2);
      a3 = fmaf(xs[wv][3][k], wkl, a3);
    }
    const float bb = B2[h*ENC_ + lane];
    const float gg = G2[h*ENC_ + lane], be = Be2[h*ENC_ + lane];
    float acc[4] = {a0 + bb, a1 + bb, a2 + bb, a3 + bb};
    float psum = 0.f;
    #pragma unroll
    for (int r = 0; r < 4; ++r) {
      const float m = wave_sum(acc[r]) * (1.f / ENC_);
      const float d = acc[r] - m;
      const float var = wave_sum(d * d) * (1.f / ENC_);
      const float y = d * rsqrtf(var + 1e-5f) * gg + be;
      psum += gelu_exact(y);
    }
    red[wv][lane] = psum;
    __syncthreads();
    if (wv == 0) {
      const float tot = red[0][lane] + red[1][lane] + red[2][lane] + red[3][lane];
      Partial[((size_t)h * NBLK_ + blockIdx.x) * ENC_ + lane] = tot;
    }
  }
}

// ---------------- reduce ctx partials + temperature + pvec, 128 threads/head ----------------
__global__ __launch_bounds__(128) void pvec_kernel(
    const float* __restrict__ Partial, const float* __restrict__ temperature,
    const float* __restrict__ w1, const float* __restrict__ b1,
    const float* __restrict__ g, const float* __restrict__ b,
    float* __restrict__ pvec, float* __restrict__ tmp)
{
  __shared__ float red[128];
  __shared__ float ctxl[ENC_];
  __shared__ float sred[2];
  const int h = blockIdx.x, tid = threadIdx.x;
  const int e = tid & 63, half = tid >> 6;
  float s = 0.f;
  const float* __restrict__ pp = Partial + (size_t)h * NBLK_ * ENC_ + e;
  #pragma unroll 4
  for (int bb = half * 64; bb < half * 64 + 64; ++bb) s += pp[(size_t)bb * ENC_];
  red[tid] = s;
  __syncthreads();
  if (half == 0) ctxl[e] = (red[e] + red[64 + e]) * (1.f / NS_);
  if (h == 0 && tid == 0) {
    const float t = fminf(fmaxf(temperature[0], 0.1f), 2.0f);
    tmp[0] = t; tmp[1] = 1.f / t;
  }
  __syncthreads();
  const int j = tid;
  float acc = b1[h * FEAT_ + j];
  #pragma unroll 4
  for (int e2 = 0; e2 < ENC_; ++e2)
    acc = fmaf(ctxl[e2], w1[((size_t)h * ENC_ + e2) * FEAT_ + j], acc);
  const int lane = j & 63, wvv = j >> 6;
  const float ps = wave_sum(acc);
  if (lane == 0) sred[wvv] = ps;
  __syncthreads();
  const float m = (sred[0] + sred[1]) * (1.f / FEAT_);
  const float d = acc - m;
  const float vs = wave_sum(d * d);
  __syncthreads();
  if (lane == 0) sred[wvv] = vs;
  __syncthreads();
  const float var = (sred[0] + sred[1]) * (1.f / FEAT_);
  const float y = d * rsqrtf(var + 1e-5f) * g[h * FEAT_ + j] + b[h * FEAT_ + j];
  pvec[h * FEAT_ + j] = gelu_exact(y);
}

// ---------------- params = tanh(p @ pg_w2 + pg_b2)*2 → W bf16 hi/lo image + sb/leaf/tree ----------------
__global__ __launch_bounds__(256) void params_kernel(
    const float* __restrict__ pvec, const float* __restrict__ w2,
    const float* __restrict__ b2, const float* __restrict__ tmp,
    char* __restrict__ WbfB, float* __restrict__ sbv,
    float* __restrict__ lraw, float* __restrict__ traw)
{
  __shared__ float pl[FEAT_];
  const int h = blockIdx.y;
  if (threadIdx.x < FEAT_) pl[threadIdx.x] = pvec[h * FEAT_ + threadIdx.x];
  __syncthreads();
  const int j4 = blockIdx.x * 1024 + threadIdx.x * 4;
  if (j4 >= P_) return;
  const float it = tmp[1];
  float4 acc = *reinterpret_cast<const float4*>(b2 + (size_t)h * P_ + j4);
  const float* __restrict__ wp = w2 + (size_t)h * FEAT_ * P_ + j4;
  #pragma unroll 4
  for (int k = 0; k < FEAT_; ++k) {
    const float pk = pl[k];
    const float4 wv = *reinterpret_cast<const float4*>(wp + (size_t)k * P_);
    acc.x = fmaf(pk, wv.x, acc.x);
    acc.y = fmaf(pk, wv.y, acc.y);
    acc.z = fmaf(pk, wv.z, acc.z);
    acc.w = fmaf(pk, wv.w, acc.w);
  }
  const float vals[4] = {acc.x, acc.y, acc.z, acc.w};
  if (j4 < SW_) {
    const int t = j4 / 3840, rem = j4 - t * 3840, i = rem >> 8, d = rem & 255;
    const int g = h * T_ + t;
    ushort4_t hs, ls;
    #pragma unroll
    for (int q = 0; q < 4; ++q) {
      const float v = tanhf(vals[q]) * 2.f * it;
      const unsigned short hb = f2bf(v);
      hs[q] = hb;
      ls[q] = f2bf(v - bf2f(hb));
    }
    const unsigned off = (unsigned)(i * 512 + d * 2) ^ ((unsigned)(i & 15) << 4);
    char* base = WbfB + (size_t)g * WGB_;
    *(ushort4_t*)(base + off) = hs;
    *(ushort4_t*)(base + 8192 + off) = ls;
  } else {
    #pragma unroll
    for (int q = 0; q < 4; ++q) {
      const int j = j4 + q;
      const float v = tanhf(vals[q]) * 2.f;
      if (j < SW_ + SB_) {
        const int jj = j - SW_;                 // 0..224 within head: t = jj/15, i = jj%15
        sbv[((size_t)h * T_ + jj / 15) * 16 + (jj % 15)] = v * it;   // padded stride 16
      }
      else if (j < SW_ + SB_ + LF_) lraw[h * LF_ + (j - SW_ - SB_)] = v;
      else                          traw[h * T_ + (j - SW_ - SB_ - LF_)] = v;
    }
  }
}

// ---------------- finalize, parallelized: one block per group ----------------
__global__ __launch_bounds__(256) void finalize_kernel(
    const float* __restrict__ head_weights, const float* __restrict__ traw,
    const float* __restrict__ lraw, const float* __restrict__ tmp,
    float* __restrict__ sl, char* __restrict__ slA, char* __restrict__ WbfB,
    float* __restrict__ sbv)
{
  const int g = blockIdx.x;          // 0..74
  const int h = g / T_;
  const int tid = threadIdx.x;
  __shared__ float wtg;
  if (tid < 128) {                   // zero pad row i=15 of this group's W image (hi+lo)
    char* base = WbfB + (size_t)g * WGB_ + 15 * 512 + tid * 4;
    *(unsigned*)base = 0u;
    *(unsigned*)(base + 8192) = 0u;
  } else if (tid == 128) {
    sbv[g * 16 + 15] = 0.f;          // sb pad slot
  } else if (tid == 129) {
    float m = -1e30f;
    for (int hh = 0; hh < H_; ++hh) m = fmaxf(m, head_weights[hh]);
    float s = 0.f;
    for (int hh = 0; hh < H_; ++hh) s += __expf(head_weights[hh] - m);
    const float hwv = __expf(head_weights[h] - m) / s;
    float mt = -1e30f;
    for (int t = 0; t < T_; ++t) mt = fmaxf(mt, traw[h * T_ + t]);
    float st = 0.f;
    for (int t = 0; t < T_; ++t) st += __expf(traw[h * T_ + t] - mt);
    wtg = hwv * __expf(traw[g] - mt) / st;
  }
  __syncthreads();
  const float it = tmp[1];
  if (tid < L_) {                    // scaled leaf softmax, one row per thread
    const int row = g * L_ + tid;
    const float* __restrict__ lr = lraw + (size_t)row * C_;
    float m = -1e30f;
    #pragma unroll
    for (int c = 0; c < C_; ++c) m = fmaxf(m, lr[c]);
    float e[C_]; float s = 0.f;
    #pragma unroll
    for (int c = 0; c < C_; ++c) { e[c] = __expf((lr[c] - m) * it); s += e[c]; }
    const float sc = wtg / s;
    #pragma unroll
    for (int c = 0; c < C_; ++c) sl[(size_t)row * C_ + c] = e[c] * sc;
  }
  __syncthreads();
  if (tid < 64) {                    // slA A-fragment image pack
    const int p = tid, c = p & 15, kg = p >> 4;
    ushort4_t w0, w1;
    #pragma unroll
    for (int j = 0; j < 8; ++j) {
      const int l = kg * 8 + j;
      const unsigned short v = (l < 16 && c < 10) ? f2bf(sl[(size_t)(g * 16 + l) * C_ + c]) : (unsigned short)0;
      if (j < 4) w0[j] = v; else w1[j - 4] = v;
    }
    *(ushort4_t*)(slA + (size_t)(g * 64 + p) * 16) = w0;
    *(ushort4_t*)(slA + (size_t)(g * 64 + p) * 16 + 8) = w1;
  }
}

// ---------------- fused MFMA query kernel: 128 q/block (4 waves x 32q = 2 tiles), GSPLIT x2 ----------------
// B-fragment ds_reads shared across 2 A-tiles (16 b128 feed 48 QK MFMA). Quad-cone epilogue per tile.
__global__ __launch_bounds__(256, 2) void qk_kernel(
    const float* __restrict__ Xq, const char* __restrict__ WbfB,
    const char* __restrict__ slA, const float* __restrict__ sbvP,
    float* __restrict__ outP)
{
  __shared__ char lds[40960];       // [0,32768): W dbuf (2x16KB); [32768,40960): 4x2KB tw
  const int tid  = threadIdx.x;
  const int lane = tid & 63;
  const int wv   = tid >> 6;
  const int n0   = blockIdx.x * 128;
  const int gc   = blockIdx.y;
  const int gbeg = gc ? 38 : 0;
  const int gend = gc ? G_ : 38;
  const int lrow = lane & 15;       // A row (query within tile) / B col (i) / leaf-A row (c)
  const int lkg  = lane >> 4;       // k-group 0..3 == leaf-quad owned

  // ---- A-fragments: 2 tiles of 16 queries (hi/lo bf16) ----
  short8 Ah[2][8], Al[2][8];
  #pragma unroll
  for (int rt = 0; rt < 2; ++rt) {
    const float* xr = Xq + (size_t)(n0 + wv * 32 + rt * 16 + lrow) * 256 + lkg * 8;
    #pragma unroll
    for (int ks = 0; ks < 8; ++ks) {
      const f32x4 a = *(const f32x4*)(xr + ks * 32);
      const f32x4 b = *(const f32x4*)(xr + ks * 32 + 4);
      short8 hh, ll;
      #pragma unroll
      for (int j = 0; j < 4; ++j) {
        unsigned short hb = f2bf(a[j]);
        hh[j] = (short)hb; ll[j] = (short)f2bf(a[j] - bf2f(hb));
        hb = f2bf(b[j]);
        hh[4 + j] = (short)hb; ll[4 + j] = (short)f2bf(b[j] - bf2f(hb));
      }
      Ah[rt][ks] = hh; Al[rt][ks] = ll;
    }
  }

  // DMA one group's 16KB W image into buf (each wave stages its 4KB segment)
  auto DMA = [&](int g, int buf) {
    const char* src = WbfB + (size_t)g * WGB_;
    char* dst = lds + buf * WGB_;
    #pragma unroll
    for (int it = 0; it < 4; ++it) {
      const int seg = wv * 4096 + it * 1024;
      gload16(src + seg + lane * 16, dst + seg);
    }
  };

  // ---- prologue: DMA first group into buf0 ----
  DMA(gbeg, 0);
  __syncthreads();                  // drains vmcnt -> buf0 ready

  char* tw = lds + 32768 + wv * 2048;   // per-wave 2-tile logit transpose (zero-conflict layout)
  const int q  = lane & 15;             // query owned in the epilogue (per tile)
  const int h2 = lkg >> 1;

  // ---- g-invariant epilogue constants (hoisted) ----
  const int sI1 = 1 + h2, sI2 = 3 + lkg, sI3 = 7 + 2 * lkg, sI4 = 8 + 2 * lkg;
  auto twAddr = [&](int c, int qt) -> unsigned {
    return (unsigned)(c * 128 + qt * 4) ^ ((unsigned)(c & 7) << 4);
  };
  const unsigned tA0_0 = twAddr(0, q),        tA0_1 = twAddr(0, 16 + q);
  const unsigned tA1_0 = twAddr(sI1, q),      tA1_1 = twAddr(sI1, 16 + q);
  const unsigned tA2_0 = twAddr(sI2, q),      tA2_1 = twAddr(sI2, 16 + q);
  const unsigned tA3_0 = twAddr(sI3, q),      tA3_1 = twAddr(sI3, 16 + q);
  const unsigned tA4_0 = twAddr(sI4, q),      tA4_1 = twAddr(sI4, 16 + q);
  const int idx0 = ((lkg & 1) << 5) + q;   // src lane for quad 2*kg
  const int idx1 = idx0 + 16;              // src lane for quad 2*kg+1
  const bool act = (lkg < 2);              // B rows k>=16 are zero
  // transpose write addresses (per tile)
  const unsigned wA0 = (unsigned)(lrow * 128 + (0 * 16 + lkg * 4) * 4) ^ ((unsigned)(lrow & 7) << 4);
  const unsigned wA1 = (unsigned)(lrow * 128 + (1 * 16 + lkg * 4) * 4) ^ ((unsigned)(lrow & 7) << 4);

  f32x4 Cac0 = {0.f, 0.f, 0.f, 0.f}, Cac1 = {0.f, 0.f, 0.f, 0.f};

  int cur = 0;
  for (int g = gbeg; g < gend; ++g) {
    // per-group operands FIRST (oldest in VMEM FIFO -> their waits never drain the DMA)
    const short8 Asl = *(const short8*)(slA + (size_t)g * 1024 + lane * 16);
    const float* sbg = sbvP + (size_t)g * 16;
    const float s0v = sbg[0], s1v = sbg[sI1], s2v = sbg[sI2], s3v = sbg[sI3], s4v = sbg[sI4];
    if (g + 1 < gend) DMA(g + 1, cur ^ 1);

    const char* bb = lds + cur * WGB_;
    // 16 shared B-frag reads feed 6 independent 8-deep chains (3 per tile)
    f32x4 Ch0 = {0,0,0,0}, Cm10 = {0,0,0,0}, Cm20 = {0,0,0,0};
    f32x4 Ch1 = {0,0,0,0}, Cm11 = {0,0,0,0}, Cm21 = {0,0,0,0};
    __builtin_amdgcn_s_setprio(1);
    #pragma unroll
    for (int ks = 0; ks < 8; ++ks) {
      const unsigned adr = (unsigned)(lrow * 512 + ks * 64 + lkg * 16) ^ ((unsigned)lrow << 4);
      const short8 bh = *(const short8*)(bb + adr);
      const short8 bl = *(const short8*)(bb + 8192 + adr);
      Ch0  = __builtin_amdgcn_mfma_f32_16x16x32_bf16(Ah[0][ks], bh, Ch0,  0, 0, 0);
      Cm10 = __builtin_amdgcn_mfma_f32_16x16x32_bf16(Ah[0][ks], bl, Cm10, 0, 0, 0);
      Cm20 = __builtin_amdgcn_mfma_f32_16x16x32_bf16(Al[0][ks], bh, Cm20, 0, 0, 0);
      Ch1  = __builtin_amdgcn_mfma_f32_16x16x32_bf16(Ah[1][ks], bh, Ch1,  0, 0, 0);
      Cm11 = __builtin_amdgcn_mfma_f32_16x16x32_bf16(Ah[1][ks], bl, Cm11, 0, 0, 0);
      Cm21 = __builtin_amdgcn_mfma_f32_16x16x32_bf16(Al[1][ks], bh, Cm21, 0, 0, 0);
    }
    __builtin_amdgcn_s_setprio(0);
    // transpose logits through per-wave LDS (both tiles)
    {
      f32x4 cs0, cs1;
      #pragma unroll
      for (int r = 0; r < 4; ++r) { cs0[r] = Ch0[r] + Cm10[r] + Cm20[r]; cs1[r] = Ch1[r] + Cm11[r] + Cm21[r]; }
      *(f32x4*)(tw + wA0) = cs0;
      *(f32x4*)(tw + wA1) = cs1;
    }
    // quad-cone epilogue per tile: 5 sigmoids + tree -> leaves 4*lkg..4*lkg+3 of query q
    auto leaf = [&](unsigned a0, unsigned a1, unsigned a2, unsigned a3, unsigned a4, f32x4& CacT) {
      const float lg0 = *(const float*)(tw + a0) + s0v;
      const float lg1 = *(const float*)(tw + a1) + s1v;
      const float lg2 = *(const float*)(tw + a2) + s2v;
      const float lg3 = *(const float*)(tw + a3) + s3v;
      const float lg4 = *(const float*)(tw + a4) + s4v;
      const float d0 = fast_rcp(1.f + __expf(-lg0));
      const float d1 = fast_rcp(1.f + __expf(-lg1));
      const float d2 = fast_rcp(1.f + __expf(-lg2));
      const float d3 = fast_rcp(1.f + __expf(-lg3));
      const float d4 = fast_rcp(1.f + __expf(-lg4));
      const float aq = (lkg >= 2) ? d0 : (1.f - d0);
      const float bq = aq * ((lkg & 1) ? d1 : (1.f - d1));
      const float c0 = bq * (1.f - d2), c1 = bq * d2;
      const float r0 = c0 * (1.f - d3), r1 = c0 * d3;
      const float r2 = c1 * (1.f - d4), r3 = c1 * d4;
      const unsigned Pa = cvt_pk_bf16(r0, r1);
      const unsigned Pb = cvt_pk_bf16(r2, r3);
      const unsigned g0w = __shfl(Pa, idx0, 64);
      const unsigned g1w = __shfl(Pb, idx0, 64);
      const unsigned g2w = __shfl(Pa, idx1, 64);
      const unsigned g3w = __shfl(Pb, idx1, 64);
      uint4_t bu;
      bu[0] = act ? g0w : 0u;
      bu[1] = act ? g1w : 0u;
      bu[2] = act ? g2w : 0u;
      bu[3] = act ? g3w : 0u;
      const short8 B0 = __builtin_bit_cast(short8, bu);
      CacT = __builtin_amdgcn_mfma_f32_16x16x32_bf16(Asl, B0, CacT, 0, 0, 0);
    };
    leaf(tA0_0, tA1_0, tA2_0, tA3_0, tA4_0, Cac0);
    leaf(tA0_1, tA1_1, tA2_1, tA3_1, tA4_1, Cac1);
    __syncthreads();                // drains DMA (g+1 ready) + all reads of buf[cur] done
    cur ^= 1;
  }

  // store partials: tile t, D[c][q] col=lane&15=q, row c=lkg*4+j
  float* base = outP + (size_t)gc * ((size_t)NQ_ * 10);
  #pragma unroll
  for (int j = 0; j < 4; ++j) {
    const int c = lkg * 4 + j;
    if (c < 10) {
      base[(size_t)(n0 + wv * 32 + q) * 10 + c]      = Cac0[j];
      base[(size_t)(n0 + wv * 32 + 16 + q) * 10 + c] = Cac1[j];
    }
  }
}

// ---------------- sum the 2 gchunk partials ----------------
__global__ __launch_bounds__(256) void reduce_kernel(const float* __restrict__ p, float* __restrict__ out)
{
  const size_t i = ((size_t)blockIdx.x * 256 + threadIdx.x) * 4;
  const f32x4 a = *(const f32x4*)(p + i);
  const f32x4 b = *(const f32x4*)(p + (size_t)NQ_ * 10 + i);
  f32x4 s;
  #pragma unroll
  for (int j = 0; j < 4; ++j) s[j] = a[j] + b[j];
  *(f32x4*)(out + i) = s;
}

// ---------------- diagnostic marker: only runs if a launch failed ----------------
__global__ void mark_kernel(float* out, float v) { out[threadIdx.x] = v; }

extern "C" void kernel_launch(void* const* d_in, const int* in_sizes, int n_in,
                              void* d_out, int out_size, void* d_ws, size_t ws_size,
                              hipStream_t stream) {
  (void)in_sizes; (void)n_in; (void)out_size;
  const float* Xs          = (const float*)d_in[0];
  const float* Xq          = (const float*)d_in[1];
  const float* enc_w1      = (const float*)d_in[2];
  const float* enc_b1      = (const float*)d_in[3];
  const float* ln1_g       = (const float*)d_in[4];
  const float* ln1_b       = (const float*)d_in[5];
  const float* enc_w2      = (const float*)d_in[6];
  const float* enc_b2      = (const float*)d_in[7];
  const float* ln2_g       = (const float*)d_in[8];
  const float* ln2_b       = (const float*)d_in[9];
  const float* pg_w1       = (const float*)d_in[10];
  const float* pg_b1       = (const float*)d_in[11];
  const float* pg_ln_g     = (const float*)d_in[12];
  const float* pg_ln_b     = (const float*)d_in[13];
  const float* pg_w2       = (const float*)d_in[14];
  const float* pg_b2       = (const float*)d_in[15];
  const float* head_wts    = (const float*)d_in[16];
  const float* temperature = (const float*)d_in[17];

  float* ws   = (float*)d_ws;
  float* cpart= ws + OFF_CP;
  float* pvec = ws + OFF_PVEC;
  float* tmp  = ws + OFF_TMP;
  float* sbp  = ws + OFF_SB;
  float* lrw  = ws + OFF_LRAW;
  float* trw  = ws + OFF_TRAW;
  float* slp  = ws + OFF_SL;
  char*  wbf  = (char*)(ws + OFF_WBF);
  char*  slA  = (char*)(ws + OFF_SLA);
  float* outP = ws + OFF_OUTP;
  float* outp = (float*)d_out;

  unsigned mask = 0;
  (void)hipGetLastError();
  if (ws_size < WS_NEED_FLOATS * sizeof(float)) mask |= 0x80u;

  if (!mask) {
    enc12_kernel<<<dim3(NBLK_, 5), 256, 0, stream>>>(Xs, enc_w1, enc_b1, ln1_g, ln1_b,
                                                     enc_w2, enc_b2, ln2_g, ln2_b, cpart);
    if (hipGetLastError() != hipSuccess) mask |= 1u;
    pvec_kernel<<<5, 128, 0, stream>>>(cpart, temperature, pg_w1, pg_b1, pg_ln_g, pg_ln_b, pvec, tmp);
    if (hipGetLastError() != hipSuccess) mask |= 2u;
    params_kernel<<<dim3(59, 5), 256, 0, stream>>>(pvec, pg_w2, pg_b2, tmp, wbf, sbp, lrw, trw);
    if (hipGetLastError() != hipSuccess) mask |= 4u;
    finalize_kernel<<<G_, 256, 0, stream>>>(head_wts, trw, lrw, tmp, slp, slA, wbf, sbp);
    if (hipGetLastError() != hipSuccess) mask |= 8u;
    qk_kernel<<<dim3(NQ_ / 128, GSPLIT_), 256, 0, stream>>>(Xq, wbf, slA, sbp, outP);
    if (hipGetLastError() != hipSuccess) mask |= 16u;
    reduce_kernel<<<(NQ_ * 10) / (256 * 4), 256, 0, stream>>>(outP, outp);
    if (hipGetLastError() != hipSuccess) mask |= 32u;
  }
  if (mask) {
    mark_kernel<<<1, 16, 0, stream>>>(outp, 1024.f + 4.f * (float)mask);
    (void)hipGetLastError();
  }
}

// Round 20
// 151.816 us; speedup vs baseline: 1.8348x; 1.0326x over previous
//
#include <hip/hip_runtime.h>

#define DEV __device__ __forceinline__

typedef __attribute__((ext_vector_type(8))) short short8;
typedef __attribute__((ext_vector_type(4))) float f32x4;
typedef __attribute__((ext_vector_type(4))) unsigned short ushort4_t;
typedef __attribute__((ext_vector_type(4))) unsigned int uint4_t;

namespace {
constexpr int D_ = 256, C_ = 10, T_ = 15, H_ = 5, ENC_ = 64, L_ = 16;
constexpr int NS_ = 2048, NQ_ = 32768;
constexpr int P_ = 60240, SW_ = 57600, SB_ = 225, LF_ = 2400;
constexpr int FEAT_ = 128;
constexpr int G_ = 75;                      // H*T groups
constexpr int GSPLIT_ = 2;                  // group chunks (38 + 37)
constexpr int WGB_ = 16384;                 // bytes per group W-image
constexpr int NBLK_ = 128;                  // encoder blocks per head

// workspace layout (in floats)
constexpr size_t OFF_CP   = 0;                                  // 5*128*64 partial ctx sums
constexpr size_t OFF_PVEC = OFF_CP + (size_t)H_*NBLK_*ENC_;
constexpr size_t OFF_TMP  = OFF_PVEC + (size_t)H_*FEAT_;
constexpr size_t OFF_SB   = OFF_TMP + 8;                        // 75*16 padded sb (stride 16)
constexpr size_t OFF_LRAW = OFF_SB + (size_t)G_*16 + 16;
constexpr size_t OFF_TRAW = OFF_LRAW + (size_t)H_*T_*L_*C_;
constexpr size_t OFF_SL   = OFF_TRAW + (size_t)H_*T_;
constexpr size_t OFF_WBF  = OFF_SL + (size_t)H_*T_*L_*C_;       // 75*16384B
constexpr size_t OFF_SLA  = OFF_WBF + (size_t)G_*WGB_/4;        // 75*1024B
constexpr size_t OFF_OUTP = OFF_SLA + (size_t)G_*1024/4;        // 2*NQ*10 partials
constexpr size_t WS_NEED_FLOATS = OFF_OUTP + (size_t)GSPLIT_*NQ_*10;
} // namespace

DEV float wave_sum(float v) {
  #pragma unroll
  for (int o = 32; o; o >>= 1) v += __shfl_xor(v, o, 64);
  return v;
}
DEV float gelu_exact(float x) { return 0.5f * x * (1.f + erff(x * 0.70710678118654752f)); }
DEV unsigned short f2bf(float x) {            // RNE bf16
  unsigned u = __float_as_uint(x);
  return (unsigned short)((u + 0x7FFFu + ((u >> 16) & 1u)) >> 16);
}
DEV float bf2f(unsigned short b) { return __uint_as_float(((unsigned)b) << 16); }
DEV unsigned cvt_pk_bf16(float lo, float hi) {
  unsigned d;
  asm("v_cvt_pk_bf16_f32 %0, %1, %2" : "=v"(d) : "v"(lo), "v"(hi));
  return d;
}
DEV float fast_rcp(float x) {                 // raw v_rcp_f32 (~1 ulp)
  float r;
  asm("v_rcp_f32 %0, %1" : "=v"(r) : "v"(x));
  return r;
}
// async global -> LDS DMA, 16B per lane; lds dest = uniform base + lane*16 (HW adds lane offset)
DEV void gload16(const char* g, char* l) {
  __builtin_amdgcn_global_load_lds(
      (const __attribute__((address_space(1))) void*)g,
      (__attribute__((address_space(3))) void*)l, 16, 0, 0);
}

// ---------------- fused encoder: enc2(enc1(X)) reduced in-block to ctx partials ----------------
__global__ __launch_bounds__(256) void enc12_kernel(
    const float* __restrict__ Xbase,
    const float* __restrict__ W1, const float* __restrict__ B1,
    const float* __restrict__ G1, const float* __restrict__ Be1,
    const float* __restrict__ W2, const float* __restrict__ B2,
    const float* __restrict__ G2, const float* __restrict__ Be2,
    float* __restrict__ Partial)
{
  __shared__ float xs[4][4][ENC_];     // [wave][row][col] = 4 KB
  __shared__ float red[4][ENC_];
  const int h = blockIdx.y;
  const int lane = threadIdx.x & 63;
  const int wv = threadIdx.x >> 6;
  const int row0 = blockIdx.x * 16 + wv * 4;

  { // ---- enc1: K=256 from global ----
    constexpr int K = 256;
    const float* __restrict__ X = Xbase + (size_t)row0 * K;
    const float* __restrict__ wc = W1 + (size_t)h * K * ENC_ + lane;
    float a0 = 0.f, a1 = 0.f, a2 = 0.f, a3 = 0.f;
    #pragma unroll 4
    for (int k = 0; k < K; ++k) {
      const float wkl = wc[(size_t)k * ENC_];
      a0 = fmaf(X[k],       wkl, a0);
      a1 = fmaf(X[K + k],   wkl, a1);
      a2 = fmaf(X[2*K + k], wkl, a2);
      a3 = fmaf(X[3*K + k], wkl, a3);
    }
    const float bb = B1[h*ENC_ + lane];
    const float gg = G1[h*ENC_ + lane], be = Be1[h*ENC_ + lane];
    float acc[4] = {a0 + bb, a1 + bb, a2 + bb, a3 + bb};
    #pragma unroll
    for (int r = 0; r < 4; ++r) {
      const float m = wave_sum(acc[r]) * (1.f / ENC_);
      const float d = acc[r] - m;
      const float var = wave_sum(d * d) * (1.f / ENC_);
      const float y = d * rsqrtf(var + 1e-5f) * gg + be;
      xs[wv][r][lane] = gelu_exact(y);
    }
  }
  __syncthreads();
  { // ---- enc2: K=64 from LDS (wave-local rows), then in-block ctx partial reduce ----
    constexpr int K = 64;
    const float* __restrict__ wc = W2 + (size_t)h * K * ENC_ + lane;
    float a0 = 0.f, a1 = 0.f, a2 = 0.f, a3 = 0.f;
    #pragma unroll 4
    for (int k = 0; k < K; ++k) {
      const float wkl = wc[(size_t)k * ENC_];
      a0 = fmaf(xs[wv][0][k], wkl, a0);
      a1 = fmaf(xs[wv][1][k], wkl, a1);
      a2 = fmaf(xs[wv][2][k], wkl, a2);
      a3 = fmaf(xs[wv][3][k], wkl, a3);
    }
    const float bb = B2[h*ENC_ + lane];
    const float gg = G2[h*ENC_ + lane], be = Be2[h*ENC_ + lane];
    float acc[4] = {a0 + bb, a1 + bb, a2 + bb, a3 + bb};
    float psum = 0.f;
    #pragma unroll
    for (int r = 0; r < 4; ++r) {
      const float m = wave_sum(acc[r]) * (1.f / ENC_);
      const float d = acc[r] - m;
      const float var = wave_sum(d * d) * (1.f / ENC_);
      const float y = d * rsqrtf(var + 1e-5f) * gg + be;
      psum += gelu_exact(y);
    }
    red[wv][lane] = psum;
    __syncthreads();
    if (wv == 0) {
      const float tot = red[0][lane] + red[1][lane] + red[2][lane] + red[3][lane];
      Partial[((size_t)h * NBLK_ + blockIdx.x) * ENC_ + lane] = tot;
    }
  }
}

// ---------------- reduce ctx partials + temperature + pvec, 128 threads/head ----------------
__global__ __launch_bounds__(128) void pvec_kernel(
    const float* __restrict__ Partial, const float* __restrict__ temperature,
    const float* __restrict__ w1, const float* __restrict__ b1,
    const float* __restrict__ g, const float* __restrict__ b,
    float* __restrict__ pvec, float* __restrict__ tmp)
{
  __shared__ float red[128];
  __shared__ float ctxl[ENC_];
  __shared__ float sred[2];
  const int h = blockIdx.x, tid = threadIdx.x;
  const int e = tid & 63, half = tid >> 6;
  float s = 0.f;
  const float* __restrict__ pp = Partial + (size_t)h * NBLK_ * ENC_ + e;
  #pragma unroll 4
  for (int bb = half * 64; bb < half * 64 + 64; ++bb) s += pp[(size_t)bb * ENC_];
  red[tid] = s;
  __syncthreads();
  if (half == 0) ctxl[e] = (red[e] + red[64 + e]) * (1.f / NS_);
  if (h == 0 && tid == 0) {
    const float t = fminf(fmaxf(temperature[0], 0.1f), 2.0f);
    tmp[0] = t; tmp[1] = 1.f / t;
  }
  __syncthreads();
  const int j = tid;
  float acc = b1[h * FEAT_ + j];
  #pragma unroll 4
  for (int e2 = 0; e2 < ENC_; ++e2)
    acc = fmaf(ctxl[e2], w1[((size_t)h * ENC_ + e2) * FEAT_ + j], acc);
  const int lane = j & 63, wvv = j >> 6;
  const float ps = wave_sum(acc);
  if (lane == 0) sred[wvv] = ps;
  __syncthreads();
  const float m = (sred[0] + sred[1]) * (1.f / FEAT_);
  const float d = acc - m;
  const float vs = wave_sum(d * d);
  __syncthreads();
  if (lane == 0) sred[wvv] = vs;
  __syncthreads();
  const float var = (sred[0] + sred[1]) * (1.f / FEAT_);
  const float y = d * rsqrtf(var + 1e-5f) * g[h * FEAT_ + j] + b[h * FEAT_ + j];
  pvec[h * FEAT_ + j] = gelu_exact(y);
}

// ---------------- params = tanh(p @ pg_w2 + pg_b2)*2 → W bf16 hi/lo image + sb/leaf/tree ----------------
__global__ __launch_bounds__(256) void params_kernel(
    const float* __restrict__ pvec, const float* __restrict__ w2,
    const float* __restrict__ b2, const float* __restrict__ tmp,
    char* __restrict__ WbfB, float* __restrict__ sbv,
    float* __restrict__ lraw, float* __restrict__ traw)
{
  __shared__ float pl[FEAT_];
  const int h = blockIdx.y;
  if (threadIdx.x < FEAT_) pl[threadIdx.x] = pvec[h * FEAT_ + threadIdx.x];
  __syncthreads();
  const int j4 = blockIdx.x * 1024 + threadIdx.x * 4;
  if (j4 >= P_) return;
  const float it = tmp[1];
  float4 acc = *reinterpret_cast<const float4*>(b2 + (size_t)h * P_ + j4);
  const float* __restrict__ wp = w2 + (size_t)h * FEAT_ * P_ + j4;
  #pragma unroll 4
  for (int k = 0; k < FEAT_; ++k) {
    const float pk = pl[k];
    const float4 wv = *reinterpret_cast<const float4*>(wp + (size_t)k * P_);
    acc.x = fmaf(pk, wv.x, acc.x);
    acc.y = fmaf(pk, wv.y, acc.y);
    acc.z = fmaf(pk, wv.z, acc.z);
    acc.w = fmaf(pk, wv.w, acc.w);
  }
  const float vals[4] = {acc.x, acc.y, acc.z, acc.w};
  if (j4 < SW_) {
    const int t = j4 / 3840, rem = j4 - t * 3840, i = rem >> 8, d = rem & 255;
    const int g = h * T_ + t;
    ushort4_t hs, ls;
    #pragma unroll
    for (int q = 0; q < 4; ++q) {
      const float v = tanhf(vals[q]) * 2.f * it;
      const unsigned short hb = f2bf(v);
      hs[q] = hb;
      ls[q] = f2bf(v - bf2f(hb));
    }
    const unsigned off = (unsigned)(i * 512 + d * 2) ^ ((unsigned)(i & 15) << 4);
    char* base = WbfB + (size_t)g * WGB_;
    *(ushort4_t*)(base + off) = hs;
    *(ushort4_t*)(base + 8192 + off) = ls;
  } else {
    #pragma unroll
    for (int q = 0; q < 4; ++q) {
      const int j = j4 + q;
      const float v = tanhf(vals[q]) * 2.f;
      if (j < SW_ + SB_) {
        const int jj = j - SW_;                 // 0..224 within head: t = jj/15, i = jj%15
        sbv[((size_t)h * T_ + jj / 15) * 16 + (jj % 15)] = v * it;   // padded stride 16
      }
      else if (j < SW_ + SB_ + LF_) lraw[h * LF_ + (j - SW_ - SB_)] = v;
      else                          traw[h * T_ + (j - SW_ - SB_ - LF_)] = v;
    }
  }
}

// ---------------- finalize, parallelized: one block per group ----------------
__global__ __launch_bounds__(256) void finalize_kernel(
    const float* __restrict__ head_weights, const float* __restrict__ traw,
    const float* __restrict__ lraw, const float* __restrict__ tmp,
    float* __restrict__ sl, char* __restrict__ slA, char* __restrict__ WbfB,
    float* __restrict__ sbv)
{
  const int g = blockIdx.x;          // 0..74
  const int h = g / T_;
  const int tid = threadIdx.x;
  __shared__ float wtg;
  if (tid < 128) {                   // zero pad row i=15 of this group's W image (hi+lo)
    char* base = WbfB + (size_t)g * WGB_ + 15 * 512 + tid * 4;
    *(unsigned*)base = 0u;
    *(unsigned*)(base + 8192) = 0u;
  } else if (tid == 128) {
    sbv[g * 16 + 15] = 0.f;          // sb pad slot
  } else if (tid == 129) {
    float m = -1e30f;
    for (int hh = 0; hh < H_; ++hh) m = fmaxf(m, head_weights[hh]);
    float s = 0.f;
    for (int hh = 0; hh < H_; ++hh) s += __expf(head_weights[hh] - m);
    const float hwv = __expf(head_weights[h] - m) / s;
    float mt = -1e30f;
    for (int t = 0; t < T_; ++t) mt = fmaxf(mt, traw[h * T_ + t]);
    float st = 0.f;
    for (int t = 0; t < T_; ++t) st += __expf(traw[h * T_ + t] - mt);
    wtg = hwv * __expf(traw[g] - mt) / st;
  }
  __syncthreads();
  const float it = tmp[1];
  if (tid < L_) {                    // scaled leaf softmax, one row per thread
    const int row = g * L_ + tid;
    const float* __restrict__ lr = lraw + (size_t)row * C_;
    float m = -1e30f;
    #pragma unroll
    for (int c = 0; c < C_; ++c) m = fmaxf(m, lr[c]);
    float e[C_]; float s = 0.f;
    #pragma unroll
    for (int c = 0; c < C_; ++c) { e[c] = __expf((lr[c] - m) * it); s += e[c]; }
    const float sc = wtg / s;
    #pragma unroll
    for (int c = 0; c < C_; ++c) sl[(size_t)row * C_ + c] = e[c] * sc;
  }
  __syncthreads();
  if (tid < 64) {                    // slA A-fragment image pack
    const int p = tid, c = p & 15, kg = p >> 4;
    ushort4_t w0, w1;
    #pragma unroll
    for (int j = 0; j < 8; ++j) {
      const int l = kg * 8 + j;
      const unsigned short v = (l < 16 && c < 10) ? f2bf(sl[(size_t)(g * 16 + l) * C_ + c]) : (unsigned short)0;
      if (j < 4) w0[j] = v; else w1[j - 4] = v;
    }
    *(ushort4_t*)(slA + (size_t)(g * 64 + p) * 16) = w0;
    *(ushort4_t*)(slA + (size_t)(g * 64 + p) * 16 + 8) = w1;
  }
}

// ---------------- fused MFMA query kernel: 128 q/block, PAIR-UNROLLED (2 groups per barrier) ----------------
// 4 W buffers (pair double-buffer) + 2 tw slots = 80KB LDS, 2 blocks/CU. Two independent
// group-DAGs per iteration: QK(g)|QK(g+1) back-to-back on the matrix pipe, EPI(g)|EPI(g+1)
// interleaved on VALU. One barrier per pair. Peeled single tail for the odd (37-group) chunk.
__global__ __launch_bounds__(256, 2) void qk_kernel(
    const float* __restrict__ Xq, const char* __restrict__ WbfB,
    const char* __restrict__ slA, const float* __restrict__ sbvP,
    float* __restrict__ outP)
{
  __shared__ char lds[81920];       // [0,65536): W 4-buf; [65536,81920): 2 tw slots x 4 waves x 2KB
  const int tid  = threadIdx.x;
  const int lane = tid & 63;
  const int wv   = tid >> 6;
  const int n0   = blockIdx.x * 128;
  const int gc   = blockIdx.y;
  const int gbeg = gc ? 38 : 0;
  const int gend = gc ? G_ : 38;
  const int lrow = lane & 15;       // A row (query within tile) / B col (i) / leaf-A row (c)
  const int lkg  = lane >> 4;       // k-group 0..3 == leaf-quad owned

  // ---- A-fragments: 2 tiles of 16 queries (hi/lo bf16) ----
  short8 Ah[2][8], Al[2][8];
  #pragma unroll
  for (int rt = 0; rt < 2; ++rt) {
    const float* xr = Xq + (size_t)(n0 + wv * 32 + rt * 16 + lrow) * 256 + lkg * 8;
    #pragma unroll
    for (int ks = 0; ks < 8; ++ks) {
      const f32x4 a = *(const f32x4*)(xr + ks * 32);
      const f32x4 b = *(const f32x4*)(xr + ks * 32 + 4);
      short8 hh, ll;
      #pragma unroll
      for (int j = 0; j < 4; ++j) {
        unsigned short hb = f2bf(a[j]);
        hh[j] = (short)hb; ll[j] = (short)f2bf(a[j] - bf2f(hb));
        hb = f2bf(b[j]);
        hh[4 + j] = (short)hb; ll[4 + j] = (short)f2bf(b[j] - bf2f(hb));
      }
      Ah[rt][ks] = hh; Al[rt][ks] = ll;
    }
  }

  // DMA one group's 16KB W image into buf (each wave stages its 4KB segment)
  auto DMA = [&](int g, int buf) {
    const char* src = WbfB + (size_t)g * WGB_;
    char* dst = lds + buf * WGB_;
    #pragma unroll
    for (int it = 0; it < 4; ++it) {
      const int seg = wv * 4096 + it * 1024;
      gload16(src + seg + lane * 16, dst + seg);
    }
  };

  char* tw0 = lds + 65536 + wv * 2048;  // per-wave tw, group-slot 0
  char* tw1 = tw0 + 8192;               // group-slot 1
  const int q  = lane & 15;             // query owned in the epilogue (per tile)
  const int h2 = lkg >> 1;

  // ---- g-invariant epilogue constants (hoisted; offsets relative to tw slot base) ----
  const int sI1 = 1 + h2, sI2 = 3 + lkg, sI3 = 7 + 2 * lkg, sI4 = 8 + 2 * lkg;
  auto twAddr = [&](int c, int qt) -> unsigned {
    return (unsigned)(c * 128 + qt * 4) ^ ((unsigned)(c & 7) << 4);
  };
  const unsigned tA0_0 = twAddr(0, q),        tA0_1 = twAddr(0, 16 + q);
  const unsigned tA1_0 = twAddr(sI1, q),      tA1_1 = twAddr(sI1, 16 + q);
  const unsigned tA2_0 = twAddr(sI2, q),      tA2_1 = twAddr(sI2, 16 + q);
  const unsigned tA3_0 = twAddr(sI3, q),      tA3_1 = twAddr(sI3, 16 + q);
  const unsigned tA4_0 = twAddr(sI4, q),      tA4_1 = twAddr(sI4, 16 + q);
  const int idx0 = ((lkg & 1) << 5) + q;   // src lane for quad 2*kg
  const int idx1 = idx0 + 16;              // src lane for quad 2*kg+1
  const bool act = (lkg < 2);              // B rows k>=16 are zero
  const unsigned wA0 = (unsigned)(lrow * 128 + (0 * 16 + lkg * 4) * 4) ^ ((unsigned)(lrow & 7) << 4);
  const unsigned wA1 = (unsigned)(lrow * 128 + (1 * 16 + lkg * 4) * 4) ^ ((unsigned)(lrow & 7) << 4);

  f32x4 Cac0 = {0.f, 0.f, 0.f, 0.f}, Cac1 = {0.f, 0.f, 0.f, 0.f};

  // QK for one group: 16 shared B-frag reads feed 6 independent 8-deep chains; transpose to twp
  auto QKT = [&](const char* bb, char* twp) {
    f32x4 Ch0 = {0,0,0,0}, Cm10 = {0,0,0,0}, Cm20 = {0,0,0,0};
    f32x4 Ch1 = {0,0,0,0}, Cm11 = {0,0,0,0}, Cm21 = {0,0,0,0};
    __builtin_amdgcn_s_setprio(1);
    #pragma unroll
    for (int ks = 0; ks < 8; ++ks) {
      const unsigned adr = (unsigned)(lrow * 512 + ks * 64 + lkg * 16) ^ ((unsigned)lrow << 4);
      const short8 bh = *(const short8*)(bb + adr);
      const short8 bl = *(const short8*)(bb + 8192 + adr);
      Ch0  = __builtin_amdgcn_mfma_f32_16x16x32_bf16(Ah[0][ks], bh, Ch0,  0, 0, 0);
      Cm10 = __builtin_amdgcn_mfma_f32_16x16x32_bf16(Ah[0][ks], bl, Cm10, 0, 0, 0);
      Cm20 = __builtin_amdgcn_mfma_f32_16x16x32_bf16(Al[0][ks], bh, Cm20, 0, 0, 0);
      Ch1  = __builtin_amdgcn_mfma_f32_16x16x32_bf16(Ah[1][ks], bh, Ch1,  0, 0, 0);
      Cm11 = __builtin_amdgcn_mfma_f32_16x16x32_bf16(Ah[1][ks], bl, Cm11, 0, 0, 0);
      Cm21 = __builtin_amdgcn_mfma_f32_16x16x32_bf16(Al[1][ks], bh, Cm21, 0, 0, 0);
    }
    __builtin_amdgcn_s_setprio(0);
    f32x4 cs0, cs1;
    #pragma unroll
    for (int r = 0; r < 4; ++r) { cs0[r] = Ch0[r] + Cm10[r] + Cm20[r]; cs1[r] = Ch1[r] + Cm11[r] + Cm21[r]; }
    *(f32x4*)(twp + wA0) = cs0;
    *(f32x4*)(twp + wA1) = cs1;
  };
  // epilogue for one group: quad-cone tree per tile, leaf MFMA accumulate
  auto EPI = [&](const char* twp, short8 AslG,
                 float s0v, float s1v, float s2v, float s3v, float s4v) {
    auto leaf = [&](unsigned a0, unsigned a1, unsigned a2, unsigned a3, unsigned a4, f32x4& CacT) {
      const float lg0 = *(const float*)(twp + a0) + s0v;
      const float lg1 = *(const float*)(twp + a1) + s1v;
      const float lg2 = *(const float*)(twp + a2) + s2v;
      const float lg3 = *(const float*)(twp + a3) + s3v;
      const float lg4 = *(const float*)(twp + a4) + s4v;
      const float d0 = fast_rcp(1.f + __expf(-lg0));
      const float d1 = fast_rcp(1.f + __expf(-lg1));
      const float d2 = fast_rcp(1.f + __expf(-lg2));
      const float d3 = fast_rcp(1.f + __expf(-lg3));
      const float d4 = fast_rcp(1.f + __expf(-lg4));
      const float aq = (lkg >= 2) ? d0 : (1.f - d0);
      const float bq = aq * ((lkg & 1) ? d1 : (1.f - d1));
      const float c0 = bq * (1.f - d2), c1 = bq * d2;
      const float r0 = c0 * (1.f - d3), r1 = c0 * d3;
      const float r2 = c1 * (1.f - d4), r3 = c1 * d4;
      const unsigned Pa = cvt_pk_bf16(r0, r1);
      const unsigned Pb = cvt_pk_bf16(r2, r3);
      const unsigned g0w = __shfl(Pa, idx0, 64);
      const unsigned g1w = __shfl(Pb, idx0, 64);
      const unsigned g2w = __shfl(Pa, idx1, 64);
      const unsigned g3w = __shfl(Pb, idx1, 64);
      uint4_t bu;
      bu[0] = act ? g0w : 0u;
      bu[1] = act ? g1w : 0u;
      bu[2] = act ? g2w : 0u;
      bu[3] = act ? g3w : 0u;
      const short8 B0 = __builtin_bit_cast(short8, bu);
      CacT = __builtin_amdgcn_mfma_f32_16x16x32_bf16(AslG, B0, CacT, 0, 0, 0);
    };
    leaf(tA0_0, tA1_0, tA2_0, tA3_0, tA4_0, Cac0);
    leaf(tA0_1, tA1_1, tA2_1, tA3_1, tA4_1, Cac1);
  };

  // ---- prologue: stage first pair into bufs 0,1 ----
  DMA(gbeg, 0);
  if (gbeg + 1 < gend) DMA(gbeg + 1, 1);
  __syncthreads();                  // pair 0 ready

  int pb = 0;                       // buffer-pair base in use (0 or 2)
  int g = gbeg;
  for (; g + 1 < gend; g += 2) {
    // operand loads for both groups of the pair
    const short8 Asl0 = *(const short8*)(slA + (size_t)g * 1024 + lane * 16);
    const short8 Asl1 = *(const short8*)(slA + (size_t)(g + 1) * 1024 + lane * 16);
    const float* sb0 = sbvP + (size_t)g * 16;
    const float* sb1 = sbvP + (size_t)(g + 1) * 16;
    const float a0v = sb0[0], a1v = sb0[sI1], a2v = sb0[sI2], a3v = sb0[sI3], a4v = sb0[sI4];
    const float b0v = sb1[0], b1v = sb1[sI1], b2v = sb1[sI2], b3v = sb1[sI3], b4v = sb1[sI4];
    // stage next pair into the other buffer pair (disjoint from pb pair)
    const int nb = pb ^ 2;
    if (g + 2 < gend) DMA(g + 2, nb);
    if (g + 3 < gend) DMA(g + 3, nb + 1);
    // two independent group-DAGs: matrix pipe fed 48 MFMAs deep, then both epilogues
    QKT(lds + pb * WGB_, tw0);
    QKT(lds + (pb + 1) * WGB_, tw1);
    EPI(tw0, Asl0, a0v, a1v, a2v, a3v, a4v);
    EPI(tw1, Asl1, b0v, b1v, b2v, b3v, b4v);
    __syncthreads();                // drains next-pair DMA + all reads of pb pair done
    pb ^= 2;
  }
  if (g < gend) {                   // peeled single tail (odd chunk)
    const short8 Asl0 = *(const short8*)(slA + (size_t)g * 1024 + lane * 16);
    const float* sb0 = sbvP + (size_t)g * 16;
    const float a0v = sb0[0], a1v = sb0[sI1], a2v = sb0[sI2], a3v = sb0[sI3], a4v = sb0[sI4];
    QKT(lds + pb * WGB_, tw0);
    EPI(tw0, Asl0, a0v, a1v, a2v, a3v, a4v);
  }

  // store partials: tile t, D[c][q] col=lane&15=q, row c=lkg*4+j
  float* base = outP + (size_t)gc * ((size_t)NQ_ * 10);
  #pragma unroll
  for (int j = 0; j < 4; ++j) {
    const int c = lkg * 4 + j;
    if (c < 10) {
      base[(size_t)(n0 + wv * 32 + q) * 10 + c]      = Cac0[j];
      base[(size_t)(n0 + wv * 32 + 16 + q) * 10 + c] = Cac1[j];
    }
  }
}

// ---------------- sum the 2 gchunk partials ----------------
__global__ __launch_bounds__(256) void reduce_kernel(const float* __restrict__ p, float* __restrict__ out)
{
  const size_t i = ((size_t)blockIdx.x * 256 + threadIdx.x) * 4;
  const f32x4 a = *(const f32x4*)(p + i);
  const f32x4 b = *(const f32x4*)(p + (size_t)NQ_ * 10 + i);
  f32x4 s;
  #pragma unroll
  for (int j = 0; j < 4; ++j) s[j] = a[j] + b[j];
  *(f32x4*)(out + i) = s;
}

// ---------------- diagnostic marker: only runs if a launch failed ----------------
__global__ void mark_kernel(float* out, float v) { out[threadIdx.x] = v; }

extern "C" void kernel_launch(void* const* d_in, const int* in_sizes, int n_in,
                              void* d_out, int out_size, void* d_ws, size_t ws_size,
                              hipStream_t stream) {
  (void)in_sizes; (void)n_in; (void)out_size;
  const float* Xs          = (const float*)d_in[0];
  const float* Xq          = (const float*)d_in[1];
  const float* enc_w1      = (const float*)d_in[2];
  const float* enc_b1      = (const float*)d_in[3];
  const float* ln1_g       = (const float*)d_in[4];
  const float* ln1_b       = (const float*)d_in[5];
  const float* enc_w2      = (const float*)d_in[6];
  const float* enc_b2      = (const float*)d_in[7];
  const float* ln2_g       = (const float*)d_in[8];
  const float* ln2_b       = (const float*)d_in[9];
  const float* pg_w1       = (const float*)d_in[10];
  const float* pg_b1       = (const float*)d_in[11];
  const float* pg_ln_g     = (const float*)d_in[12];
  const float* pg_ln_b     = (const float*)d_in[13];
  const float* pg_w2       = (const float*)d_in[14];
  const float* pg_b2       = (const float*)d_in[15];
  const float* head_wts    = (const float*)d_in[16];
  const float* temperature = (const float*)d_in[17];

  float* ws   = (float*)d_ws;
  float* cpart= ws + OFF_CP;
  float* pvec = ws + OFF_PVEC;
  float* tmp  = ws + OFF_TMP;
  float* sbp  = ws + OFF_SB;
  float* lrw  = ws + OFF_LRAW;
  float* trw  = ws + OFF_TRAW;
  float* slp  = ws + OFF_SL;
  char*  wbf  = (char*)(ws + OFF_WBF);
  char*  slA  = (char*)(ws + OFF_SLA);
  float* outP = ws + OFF_OUTP;
  float* outp = (float*)d_out;

  unsigned mask = 0;
  (void)hipGetLastError();
  if (ws_size < WS_NEED_FLOATS * sizeof(float)) mask |= 0x80u;

  if (!mask) {
    enc12_kernel<<<dim3(NBLK_, 5), 256, 0, stream>>>(Xs, enc_w1, enc_b1, ln1_g, ln1_b,
                                                     enc_w2, enc_b2, ln2_g, ln2_b, cpart);
    if (hipGetLastError() != hipSuccess) mask |= 1u;
    pvec_kernel<<<5, 128, 0, stream>>>(cpart, temperature, pg_w1, pg_b1, pg_ln_g, pg_ln_b, pvec, tmp);
    if (hipGetLastError() != hipSuccess) mask |= 2u;
    params_kernel<<<dim3(59, 5), 256, 0, stream>>>(pvec, pg_w2, pg_b2, tmp, wbf, sbp, lrw, trw);
    if (hipGetLastError() != hipSuccess) mask |= 4u;
    finalize_kernel<<<G_, 256, 0, stream>>>(head_wts, trw, lrw, tmp, slp, slA, wbf, sbp);
    if (hipGetLastError() != hipSuccess) mask |= 8u;
    qk_kernel<<<dim3(NQ_ / 128, GSPLIT_), 256, 0, stream>>>(Xq, wbf, slA, sbp, outP);
    if (hipGetLastError() != hipSuccess) mask |= 16u;
    reduce_kernel<<<(NQ_ * 10) / (256 * 4), 256, 0, stream>>>(outP, outp);
    if (hipGetLastError() != hipSuccess) mask |= 32u;
  }
  if (mask) {
    mark_kernel<<<1, 16, 0, stream>>>(outp, 1024.f + 4.f * (float)mask);
    (void)hipGetLastError();
  }
}